// Round 2
// baseline (8180.812 us; speedup 1.0000x reference)
//
#include <hip/hip_runtime.h>
#include <hip/hip_bf16.h>

typedef _Float16 fp16_t;
typedef _Float16 v8h __attribute__((ext_vector_type(8)));
typedef float    v4f __attribute__((ext_vector_type(4)));

#define RELAX_LR 0.3f

// ---------------------------------------------------------------------------
// Fused GEMM + state update (fp16 operands, fp32 MFMA accumulation).
// C[m,n] = sum_k A1[m,k]*B1t[n,k]  (+ sum_k A2[m,k]*B2t[n,k] if K2>0)
// init   (do_update=0): s = clip(C + bias, 0, 1)
// update (do_update=1): s = clip(s_old + LR*(C + bias - s_old), 0, 1)
// Writes s to fp32 buffer (recurrence) and fp16 buffer (next GEMM operand).
// M=1024. Tiles: BM=64 (grid.y), BN=128 (grid.x), BK=32. 128 thr = 2 waves,
// each wave computes 64x64 via 4x4 grid of 16x16x32 f16 MFMAs.
// ---------------------------------------------------------------------------
__global__ __launch_bounds__(128) void gemm_update_kernel(
    const fp16_t* __restrict__ A1, const fp16_t* __restrict__ B1t, int K1,
    const fp16_t* __restrict__ A2, const fp16_t* __restrict__ B2t, int K2,
    const float* __restrict__ bias, const float* s_old,
    float* outf, fp16_t* __restrict__ outb,
    int Ntot, int do_update)
{
    // LDS tiles, rows padded to 40 fp16 (stride 20 words -> 2-way bank alias only)
    __shared__ __align__(16) fp16_t As[64][40];
    __shared__ __align__(16) fp16_t Bs[128][40];

    const int tid  = threadIdx.x;
    const int lane = tid & 63;
    const int w    = tid >> 6;     // wave 0..1 -> n-half of tile
    const int quad = lane >> 4;    // 0..3
    const int lrow = lane & 15;

    const int bm = blockIdx.y;     // 64-row stripe of M=1024
    const int bn = blockIdx.x;     // 128-col stripe of Ntot

    v4f acc[4][4] = {};

    const int srow = tid >> 2;           // 0..31: staging row group
    const int schk = (tid & 3) * 8;      // 16B chunk within BK=32

    for (int sec = 0; sec < 2; ++sec) {
        const fp16_t* A  = sec ? A2 : A1;
        const fp16_t* Bt = sec ? B2t : B1t;
        const int K      = sec ? K2 : K1;
        if (K == 0) continue;

        const fp16_t* ap0 = A  + (size_t)(bm * 64  + srow) * K + schk;
        const fp16_t* ap1 = ap0 + (size_t)32 * K;
        const fp16_t* bp0 = Bt + (size_t)(bn * 128 + srow) * K + schk;
        const fp16_t* bp1 = bp0 + (size_t)32 * K;
        const fp16_t* bp2 = bp0 + (size_t)64 * K;
        const fp16_t* bp3 = bp0 + (size_t)96 * K;

        const int iters = K >> 5;
        for (int it = 0; it < iters; ++it) {
            __syncthreads();
            *(uint4*)&As[srow     ][schk] = *(const uint4*)ap0;
            *(uint4*)&As[srow + 32][schk] = *(const uint4*)ap1;
            *(uint4*)&Bs[srow     ][schk] = *(const uint4*)bp0;
            *(uint4*)&Bs[srow + 32][schk] = *(const uint4*)bp1;
            *(uint4*)&Bs[srow + 64][schk] = *(const uint4*)bp2;
            *(uint4*)&Bs[srow + 96][schk] = *(const uint4*)bp3;
            ap0 += 32; ap1 += 32; bp0 += 32; bp1 += 32; bp2 += 32; bp3 += 32;
            __syncthreads();

            v8h af[4], bv[4];
            #pragma unroll
            for (int fm = 0; fm < 4; ++fm)
                af[fm] = *(const v8h*)&As[fm * 16 + lrow][quad * 8];
            #pragma unroll
            for (int fn = 0; fn < 4; ++fn)
                bv[fn] = *(const v8h*)&Bs[w * 64 + fn * 16 + lrow][quad * 8];
            #pragma unroll
            for (int fm = 0; fm < 4; ++fm)
                #pragma unroll
                for (int fn = 0; fn < 4; ++fn)
                    acc[fm][fn] = __builtin_amdgcn_mfma_f32_16x16x32_f16(
                        af[fm], bv[fn], acc[fm][fn], 0, 0, 0);
        }
    }

    // Epilogue. C/D layout (verified m89): col = lane&15, row = quad*4 + reg.
    const int rowbase = bm * 64 + quad * 4;
    const int colbase = bn * 128 + w * 64;
    #pragma unroll
    for (int fn = 0; fn < 4; ++fn) {
        const int col = colbase + fn * 16 + lrow;
        const float bvv = bias[col];
        #pragma unroll
        for (int fm = 0; fm < 4; ++fm) {
            const int row = rowbase + fm * 16;
            #pragma unroll
            for (int r = 0; r < 4; ++r) {
                const size_t idx = (size_t)(row + r) * Ntot + col;
                float v = acc[fm][fn][r] + bvv;
                if (do_update) {
                    const float so = s_old[idx];
                    v = so + RELAX_LR * (v - so);
                }
                v = fminf(fmaxf(v, 0.f), 1.f);
                outf[idx] = v;
                outb[idx] = (fp16_t)v;
            }
        }
    }
}

// fp32 W [R,C] -> fp16 Wb [Rp,Cp] (same layout) + fp16 WbT [Cp,Rp] (transposed),
// zero-padded. 32x32 tiles via LDS for coalesced transposed writes.
__global__ void conv_w_kernel(const float* __restrict__ W, int R, int C,
                              fp16_t* __restrict__ Wb, fp16_t* __restrict__ WbT,
                              int Rp, int Cp)
{
    __shared__ float t[32][33];
    const int tx = threadIdx.x & 31;
    const int ty = threadIdx.x >> 5;   // 0..7
    const int r0 = blockIdx.y * 32;
    const int c0 = blockIdx.x * 32;
    #pragma unroll
    for (int i = 0; i < 4; ++i) {
        const int r = r0 + ty + i * 8;
        const int c = c0 + tx;
        float v = 0.f;
        if (r < R && c < C) v = W[(size_t)r * C + c];
        t[ty + i * 8][tx] = v;
    }
    __syncthreads();
    #pragma unroll
    for (int i = 0; i < 4; ++i) {
        const int r = r0 + ty + i * 8;
        const int c = c0 + tx;
        if (r < Rp && c < Cp) Wb[(size_t)r * Cp + c] = (fp16_t)t[ty + i * 8][tx];
    }
    #pragma unroll
    for (int i = 0; i < 4; ++i) {
        const int cc = c0 + ty + i * 8;
        const int rr = r0 + tx;
        if (cc < Cp && rr < Rp) WbT[(size_t)cc * Rp + rr] = (fp16_t)t[tx][ty + i * 8];
    }
}

// xb = fp16(x) (forward init uses raw x), rxb = fp16(clip(x,0,1)) (sweeps use rho(x))
__global__ void conv_x_kernel(const float* __restrict__ x,
                              fp16_t* __restrict__ xb, fp16_t* __restrict__ rxb, int n)
{
    const int i = blockIdx.x * blockDim.x + threadIdx.x;
    if (i < n) {
        const float v = x[i];
        xb[i]  = (fp16_t)v;
        rxb[i] = (fp16_t)fminf(fmaxf(v, 0.f), 1.f);
    }
}

__global__ void pad_b4_kernel(const float* __restrict__ b4, float* __restrict__ b4p)
{
    const int i = blockIdx.x * blockDim.x + threadIdx.x;  // 1024 threads
    if (i < 1024) b4p[i] = (i < 1000) ? b4[i] : 0.f;
}

__global__ void out_copy_kernel(const float* __restrict__ s4f, float* __restrict__ out)
{
    const int i = blockIdx.x * blockDim.x + threadIdx.x;
    if (i < 1024 * 1000) {
        const int row = i / 1000;
        const int col = i - row * 1000;
        out[i] = s4f[(size_t)row * 1024 + col];
    }
}

extern "C" void kernel_launch(void* const* d_in, const int* in_sizes, int n_in,
                              void* d_out, int out_size, void* d_ws, size_t ws_size,
                              hipStream_t stream)
{
    const float* x  = (const float*)d_in[0];
    const float* W0 = (const float*)d_in[1];
    const float* W1 = (const float*)d_in[2];
    const float* W2 = (const float*)d_in[3];
    const float* W3 = (const float*)d_in[4];
    const float* b1 = (const float*)d_in[5];
    const float* b2 = (const float*)d_in[6];
    const float* b3 = (const float*)d_in[7];
    const float* b4 = (const float*)d_in[8];
    float* out = (float*)d_out;

    char* p = (char*)d_ws;
    auto alloc = [&](size_t bytes) {
        char* q = p;
        p += (bytes + 255) & ~(size_t)255;
        return q;
    };

    // fp16 operand buffers
    fp16_t* xb   = (fp16_t*)alloc((size_t)1024 * 2048 * 2);
    fp16_t* rxb  = (fp16_t*)alloc((size_t)1024 * 2048 * 2);
    fp16_t* Wb0  = (fp16_t*)alloc((size_t)2048 * 2048 * 2);
    fp16_t* Wb1  = (fp16_t*)alloc((size_t)2048 * 2048 * 2);
    fp16_t* Wb2  = (fp16_t*)alloc((size_t)2048 * 2048 * 2);
    fp16_t* Wb3  = (fp16_t*)alloc((size_t)2048 * 1024 * 2);   // padded cols
    fp16_t* WbT0 = (fp16_t*)alloc((size_t)2048 * 2048 * 2);
    fp16_t* WbT1 = (fp16_t*)alloc((size_t)2048 * 2048 * 2);
    fp16_t* WbT2 = (fp16_t*)alloc((size_t)2048 * 2048 * 2);
    fp16_t* WbT3 = (fp16_t*)alloc((size_t)1024 * 2048 * 2);   // padded rows
    // states: fp32 (recurrence) + fp16 (GEMM operand)
    float*  s1f  = (float*)alloc((size_t)1024 * 2048 * 4);
    float*  s2f  = (float*)alloc((size_t)1024 * 2048 * 4);
    float*  s3f  = (float*)alloc((size_t)1024 * 2048 * 4);
    float*  s4f  = (float*)alloc((size_t)1024 * 1024 * 4);
    fp16_t* s1b  = (fp16_t*)alloc((size_t)1024 * 2048 * 2);
    fp16_t* s2b  = (fp16_t*)alloc((size_t)1024 * 2048 * 2);
    fp16_t* s3b  = (fp16_t*)alloc((size_t)1024 * 2048 * 2);
    fp16_t* s4b  = (fp16_t*)alloc((size_t)1024 * 1024 * 2);
    float*  b4p  = (float*)alloc(1024 * 4);
    (void)ws_size; (void)in_sizes; (void)n_in; (void)out_size;

    // --- setup: conversions (recomputed every call; same work each call) ---
    conv_x_kernel<<<(1024 * 2048 + 255) / 256, 256, 0, stream>>>(x, xb, rxb, 1024 * 2048);
    pad_b4_kernel<<<4, 256, 0, stream>>>(b4, b4p);
    conv_w_kernel<<<dim3(64, 64), 256, 0, stream>>>(W0, 2048, 2048, Wb0, WbT0, 2048, 2048);
    conv_w_kernel<<<dim3(64, 64), 256, 0, stream>>>(W1, 2048, 2048, Wb1, WbT1, 2048, 2048);
    conv_w_kernel<<<dim3(64, 64), 256, 0, stream>>>(W2, 2048, 2048, Wb2, WbT2, 2048, 2048);
    conv_w_kernel<<<dim3(32, 64), 256, 0, stream>>>(W3, 2048, 1000, Wb3, WbT3, 2048, 1024);

    const dim3 blk(128);
    const dim3 g2048(2048 / 128, 1024 / 64);  // 256 blocks
    const dim3 g1024(1024 / 128, 1024 / 64);  // 128 blocks

    // --- feedforward init: s_l = clip(s_{l-1} @ W_{l-1} + b_l, 0, 1) ---
    gemm_update_kernel<<<g2048, blk, 0, stream>>>(xb,  WbT0, 2048, nullptr, nullptr, 0,
                                                  b1, nullptr, s1f, s1b, 2048, 0);
    gemm_update_kernel<<<g2048, blk, 0, stream>>>(s1b, WbT1, 2048, nullptr, nullptr, 0,
                                                  b2, nullptr, s2f, s2b, 2048, 0);
    gemm_update_kernel<<<g2048, blk, 0, stream>>>(s2b, WbT2, 2048, nullptr, nullptr, 0,
                                                  b3, nullptr, s3f, s3b, 2048, 0);
    gemm_update_kernel<<<g1024, blk, 0, stream>>>(s3b, WbT3, 2048, nullptr, nullptr, 0,
                                                  b4p, nullptr, s4f, s4b, 1024, 0);

    // --- 25 Gauss-Seidel sweeps (states post-rho => rho is identity on them) ---
    for (int it = 0; it < 25; ++it) {
        gemm_update_kernel<<<g2048, blk, 0, stream>>>(rxb, WbT0, 2048, s2b, Wb1, 2048,
                                                      b1, s1f, s1f, s1b, 2048, 1);
        gemm_update_kernel<<<g2048, blk, 0, stream>>>(s1b, WbT1, 2048, s3b, Wb2, 2048,
                                                      b2, s2f, s2f, s2b, 2048, 1);
        gemm_update_kernel<<<g2048, blk, 0, stream>>>(s2b, WbT2, 2048, s4b, Wb3, 1024,
                                                      b3, s3f, s3f, s3b, 2048, 1);
        gemm_update_kernel<<<g1024, blk, 0, stream>>>(s3b, WbT3, 2048, nullptr, nullptr, 0,
                                                      b4p, s4f, s4f, s4b, 1024, 1);
    }

    // --- strip padding into d_out [1024,1000] ---
    out_copy_kernel<<<(1024 * 1000 + 255) / 256, 256, 0, stream>>>(s4f, out);
}

// Round 3
// 3562.813 us; speedup vs baseline: 2.2962x; 2.2962x over previous
//
#include <hip/hip_runtime.h>
#include <hip/hip_bf16.h>

typedef _Float16 fp16_t;
typedef _Float16 v8h __attribute__((ext_vector_type(8)));
typedef _Float16 v4h __attribute__((ext_vector_type(4)));
typedef float    v4f __attribute__((ext_vector_type(4)));

#define RELAX_LR 0.3f

// async global->LDS, 16B per lane. LDS dest = wave-uniform base + lane*16.
__device__ __forceinline__ void async_cp16(const void* g, void* l) {
    __builtin_amdgcn_global_load_lds(
        (const __attribute__((address_space(1))) void*)g,
        (__attribute__((address_space(3))) void*)l, 16, 0, 0);
}

// ---------------------------------------------------------------------------
// Split-K GEMM into fp32 partials.
// Concatenated K-space [0,K1) -> A1*B1t^T, [K1,K1+K2) -> A2*B2t^T.
// Block z handles K-chunk [z*CK, (z+1)*CK) (never crosses the K1 boundary by
// construction of the launch). Tile: BM=128 x BN=128 x BK=32, 256 thr = 4
// waves, each wave a 64x64 quadrant via 4x4 16x16x32 f16 MFMAs.
// Staging: global_load_lds width=16; LDS [row][32] unpadded (layout must be
// lane-contiguous for global_load_lds; 2-way bank alias is free per m136).
// ---------------------------------------------------------------------------
__global__ __launch_bounds__(256, 2) void gemm_splitk_kernel(
    const fp16_t* __restrict__ A1, const fp16_t* __restrict__ B1t, int K1,
    const fp16_t* __restrict__ A2, const fp16_t* __restrict__ B2t, int K2s,
    int CK, float* __restrict__ part, int Ntot)
{
    __shared__ __align__(16) fp16_t As[128][32];
    __shared__ __align__(16) fp16_t Bs[128][32];

    const int tid  = threadIdx.x;
    const int lane = tid & 63;
    const int w    = tid >> 6;         // wave 0..3
    const int wm   = w >> 1;           // wave row-half
    const int wn   = w & 1;            // wave col-half
    const int quad = lane >> 4;
    const int lrow = lane & 15;
    const int bm = blockIdx.y, bn = blockIdx.x, z = blockIdx.z;

    int koff = z * CK;
    const fp16_t* A; const fp16_t* Bt; int stride;
    if (koff < K1) { A = A1; Bt = B1t; stride = K1; }
    else           { A = A2; Bt = B2t; stride = K2s; koff -= K1; }

    // staging: wave w owns rows [32w, 32w+32) of both tiles, two 1KB insts each.
    // lane -> (row = +lane/4, col = (lane&3)*8), matching LDS base+lane*16.
    const int sr = lane >> 2;
    const int sc = (lane & 3) * 8;
    const fp16_t* ag = A  + (size_t)(bm * 128 + 32 * w + sr) * stride + koff + sc;
    const fp16_t* bg = Bt + (size_t)(bn * 128 + 32 * w + sr) * stride + koff + sc;
    const size_t step16 = (size_t)16 * stride;

    fp16_t* al0 = &As[32 * w][0];
    fp16_t* al1 = &As[32 * w + 16][0];
    fp16_t* bl0 = &Bs[32 * w][0];
    fp16_t* bl1 = &Bs[32 * w + 16][0];

    v4f acc[4][4] = {};

    const int iters = CK >> 5;
    for (int it = 0; it < iters; ++it) {
        __syncthreads();                 // compute(it-1) done before overwrite
        async_cp16(ag,          al0);
        async_cp16(ag + step16, al1);
        async_cp16(bg,          bl0);
        async_cp16(bg + step16, bl1);
        ag += 32; bg += 32;
        __syncthreads();                 // drains vmcnt -> LDS visible

        v8h af[4], bv[4];
        #pragma unroll
        for (int fm = 0; fm < 4; ++fm)
            af[fm] = *(const v8h*)&As[wm * 64 + fm * 16 + lrow][quad * 8];
        #pragma unroll
        for (int fn = 0; fn < 4; ++fn)
            bv[fn] = *(const v8h*)&Bs[wn * 64 + fn * 16 + lrow][quad * 8];
        #pragma unroll
        for (int fm = 0; fm < 4; ++fm)
            #pragma unroll
            for (int fn = 0; fn < 4; ++fn)
                acc[fm][fn] = __builtin_amdgcn_mfma_f32_16x16x32_f16(
                    af[fm], bv[fn], acc[fm][fn], 0, 0, 0);
    }

    // write fp32 partials. C/D layout: col = lane&15, row = quad*4 + reg.
    float* po = part + (size_t)z * 1024 * Ntot;
    const int rowbase = bm * 128 + wm * 64 + quad * 4;
    const int colbase = bn * 128 + wn * 64;
    #pragma unroll
    for (int fn = 0; fn < 4; ++fn) {
        const int col = colbase + fn * 16 + lrow;
        #pragma unroll
        for (int fm = 0; fm < 4; ++fm) {
            const int row = rowbase + fm * 16;
            #pragma unroll
            for (int r = 0; r < 4; ++r)
                po[(size_t)(row + r) * Ntot + col] = acc[fm][fn][r];
        }
    }
}

// ---------------------------------------------------------------------------
// Sum nz partials + bias, then init/update + clip, dual-precision state write.
// 4 elements per thread, float4 loads. Ntot is a power of two.
// ---------------------------------------------------------------------------
__global__ __launch_bounds__(256) void reduce_update_kernel(
    const float* __restrict__ part, int nz,
    const float* __restrict__ bias, const float* __restrict__ s_old,
    float* __restrict__ outf, fp16_t* __restrict__ outb,
    int Ntot, int do_update, int total4)
{
    const int i = blockIdx.x * 256 + threadIdx.x;
    if (i >= total4) return;
    const size_t e = (size_t)i * 4;

    float4 a = *(const float4*)(part + e);
    for (int z = 1; z < nz; ++z) {
        const float4 p = *(const float4*)(part + (size_t)z * 1024 * Ntot + e);
        a.x += p.x; a.y += p.y; a.z += p.z; a.w += p.w;
    }
    const int col = (int)e & (Ntot - 1);
    const float4 bv = *(const float4*)(bias + col);
    float v[4] = {a.x + bv.x, a.y + bv.y, a.z + bv.z, a.w + bv.w};
    if (do_update) {
        const float4 so = *(const float4*)(s_old + e);
        v[0] = so.x + RELAX_LR * (v[0] - so.x);
        v[1] = so.y + RELAX_LR * (v[1] - so.y);
        v[2] = so.z + RELAX_LR * (v[2] - so.z);
        v[3] = so.w + RELAX_LR * (v[3] - so.w);
    }
    float4 o;
    o.x = fminf(fmaxf(v[0], 0.f), 1.f);
    o.y = fminf(fmaxf(v[1], 0.f), 1.f);
    o.z = fminf(fmaxf(v[2], 0.f), 1.f);
    o.w = fminf(fmaxf(v[3], 0.f), 1.f);
    *(float4*)(outf + e) = o;
    v4h h = {(fp16_t)o.x, (fp16_t)o.y, (fp16_t)o.z, (fp16_t)o.w};
    *(v4h*)(outb + e) = h;
}

// fp32 W [R,C] -> fp16 Wb [Rp,Cp] (optional) + fp16 WbT [Cp,Rp], zero-padded.
__global__ void conv_w_kernel(const float* __restrict__ W, int R, int C,
                              fp16_t* Wb, fp16_t* __restrict__ WbT,
                              int Rp, int Cp)
{
    __shared__ float t[32][33];
    const int tx = threadIdx.x & 31;
    const int ty = threadIdx.x >> 5;   // 0..7
    const int r0 = blockIdx.y * 32;
    const int c0 = blockIdx.x * 32;
    #pragma unroll
    for (int i = 0; i < 4; ++i) {
        const int r = r0 + ty + i * 8;
        const int c = c0 + tx;
        float v = 0.f;
        if (r < R && c < C) v = W[(size_t)r * C + c];
        t[ty + i * 8][tx] = v;
    }
    __syncthreads();
    if (Wb) {
        #pragma unroll
        for (int i = 0; i < 4; ++i) {
            const int r = r0 + ty + i * 8;
            const int c = c0 + tx;
            if (r < Rp && c < Cp) Wb[(size_t)r * Cp + c] = (fp16_t)t[ty + i * 8][tx];
        }
    }
    #pragma unroll
    for (int i = 0; i < 4; ++i) {
        const int cc = c0 + ty + i * 8;
        const int rr = r0 + tx;
        if (cc < Cp && rr < Rp) WbT[(size_t)cc * Rp + rr] = (fp16_t)t[tx][ty + i * 8];
    }
}

__global__ void conv_x_kernel(const float* __restrict__ x,
                              fp16_t* __restrict__ xb, fp16_t* __restrict__ rxb, int n)
{
    const int i = blockIdx.x * blockDim.x + threadIdx.x;
    if (i < n) {
        const float v = x[i];
        xb[i]  = (fp16_t)v;
        rxb[i] = (fp16_t)fminf(fmaxf(v, 0.f), 1.f);
    }
}

__global__ void pad_b4_kernel(const float* __restrict__ b4, float* __restrict__ b4p)
{
    const int i = blockIdx.x * blockDim.x + threadIdx.x;
    if (i < 1024) b4p[i] = (i < 1000) ? b4[i] : 0.f;
}

__global__ void out_copy_kernel(const float* __restrict__ s4f, float* __restrict__ out)
{
    const int i = blockIdx.x * blockDim.x + threadIdx.x;
    if (i < 1024 * 1000) {
        const int row = i / 1000;
        const int col = i - row * 1000;
        out[i] = s4f[(size_t)row * 1024 + col];
    }
}

extern "C" void kernel_launch(void* const* d_in, const int* in_sizes, int n_in,
                              void* d_out, int out_size, void* d_ws, size_t ws_size,
                              hipStream_t stream)
{
    const float* x  = (const float*)d_in[0];
    const float* W0 = (const float*)d_in[1];
    const float* W1 = (const float*)d_in[2];
    const float* W2 = (const float*)d_in[3];
    const float* W3 = (const float*)d_in[4];
    const float* b1 = (const float*)d_in[5];
    const float* b2 = (const float*)d_in[6];
    const float* b3 = (const float*)d_in[7];
    const float* b4 = (const float*)d_in[8];
    float* out = (float*)d_out;

    char* p = (char*)d_ws;
    auto alloc = [&](size_t bytes) {
        char* q = p;
        p += (bytes + 255) & ~(size_t)255;
        return q;
    };

    fp16_t* xb   = (fp16_t*)alloc((size_t)1024 * 2048 * 2);
    fp16_t* rxb  = (fp16_t*)alloc((size_t)1024 * 2048 * 2);
    fp16_t* Wb1  = (fp16_t*)alloc((size_t)2048 * 2048 * 2);
    fp16_t* Wb2  = (fp16_t*)alloc((size_t)2048 * 2048 * 2);
    fp16_t* Wb3  = (fp16_t*)alloc((size_t)2048 * 1024 * 2);   // padded cols
    fp16_t* WbT0 = (fp16_t*)alloc((size_t)2048 * 2048 * 2);
    fp16_t* WbT1 = (fp16_t*)alloc((size_t)2048 * 2048 * 2);
    fp16_t* WbT2 = (fp16_t*)alloc((size_t)2048 * 2048 * 2);
    fp16_t* WbT3 = (fp16_t*)alloc((size_t)1024 * 2048 * 2);   // padded rows
    float*  s1f  = (float*)alloc((size_t)1024 * 2048 * 4);
    float*  s2f  = (float*)alloc((size_t)1024 * 2048 * 4);
    float*  s3f  = (float*)alloc((size_t)1024 * 2048 * 4);
    float*  s4f  = (float*)alloc((size_t)1024 * 1024 * 4);
    fp16_t* s1b  = (fp16_t*)alloc((size_t)1024 * 2048 * 2);
    fp16_t* s2b  = (fp16_t*)alloc((size_t)1024 * 2048 * 2);
    fp16_t* s3b  = (fp16_t*)alloc((size_t)1024 * 2048 * 2);
    fp16_t* s4b  = (fp16_t*)alloc((size_t)1024 * 1024 * 2);
    float*  b4p  = (float*)alloc(1024 * 4);
    float*  part = (float*)alloc((size_t)8 * 1024 * 1024 * 4); // 32 MB, reused
    (void)ws_size; (void)in_sizes; (void)n_in; (void)out_size;

    // --- setup conversions ---
    conv_x_kernel<<<(1024 * 2048 + 255) / 256, 256, 0, stream>>>(x, xb, rxb, 1024 * 2048);
    pad_b4_kernel<<<4, 256, 0, stream>>>(b4, b4p);
    conv_w_kernel<<<dim3(64, 64), 256, 0, stream>>>(W0, 2048, 2048, nullptr, WbT0, 2048, 2048);
    conv_w_kernel<<<dim3(64, 64), 256, 0, stream>>>(W1, 2048, 2048, Wb1, WbT1, 2048, 2048);
    conv_w_kernel<<<dim3(64, 64), 256, 0, stream>>>(W2, 2048, 2048, Wb2, WbT2, 2048, 2048);
    conv_w_kernel<<<dim3(32, 64), 256, 0, stream>>>(W3, 2048, 1000, Wb3, WbT3, 2048, 1024);

    const dim3 blk(256);
    const int t4_2048 = 1024 * 2048 / 4;   // reduce threads (x4 elems)
    const int t4_1024 = 1024 * 1024 / 4;
    const dim3 rblk(256);
    const int rg2048 = t4_2048 / 256;      // 2048 blocks
    const int rg1024 = t4_1024 / 256;      // 1024 blocks

    // --- feedforward init (single GEMM, K=2048, split 4x512 / 8x256) ---
    gemm_splitk_kernel<<<dim3(16, 8, 4), blk, 0, stream>>>(xb,  WbT0, 2048, nullptr, nullptr, 0, 512, part, 2048);
    reduce_update_kernel<<<rg2048, rblk, 0, stream>>>(part, 4, b1, nullptr, s1f, s1b, 2048, 0, t4_2048);
    gemm_splitk_kernel<<<dim3(16, 8, 4), blk, 0, stream>>>(s1b, WbT1, 2048, nullptr, nullptr, 0, 512, part, 2048);
    reduce_update_kernel<<<rg2048, rblk, 0, stream>>>(part, 4, b2, nullptr, s2f, s2b, 2048, 0, t4_2048);
    gemm_splitk_kernel<<<dim3(16, 8, 4), blk, 0, stream>>>(s2b, WbT2, 2048, nullptr, nullptr, 0, 512, part, 2048);
    reduce_update_kernel<<<rg2048, rblk, 0, stream>>>(part, 4, b3, nullptr, s3f, s3b, 2048, 0, t4_2048);
    gemm_splitk_kernel<<<dim3(8, 8, 8), blk, 0, stream>>>(s3b, WbT3, 2048, nullptr, nullptr, 0, 256, part, 1024);
    reduce_update_kernel<<<rg1024, rblk, 0, stream>>>(part, 8, b4p, nullptr, s4f, s4b, 1024, 0, t4_1024);

    // --- 25 Gauss-Seidel sweeps ---
    for (int it = 0; it < 25; ++it) {
        // layer 1: rho(x)@W0 + s2@W1^T
        gemm_splitk_kernel<<<dim3(16, 8, 4), blk, 0, stream>>>(rxb, WbT0, 2048, s2b, Wb1, 2048, 1024, part, 2048);
        reduce_update_kernel<<<rg2048, rblk, 0, stream>>>(part, 4, b1, s1f, s1f, s1b, 2048, 1, t4_2048);
        // layer 2: s1@W1 + s3@W2^T
        gemm_splitk_kernel<<<dim3(16, 8, 4), blk, 0, stream>>>(s1b, WbT1, 2048, s3b, Wb2, 2048, 1024, part, 2048);
        reduce_update_kernel<<<rg2048, rblk, 0, stream>>>(part, 4, b2, s2f, s2f, s2b, 2048, 1, t4_2048);
        // layer 3: s2@W2 + s4@W3^T (K2=1024)
        gemm_splitk_kernel<<<dim3(16, 8, 3), blk, 0, stream>>>(s2b, WbT2, 2048, s4b, Wb3, 1024, 1024, part, 2048);
        reduce_update_kernel<<<rg2048, rblk, 0, stream>>>(part, 3, b3, s3f, s3f, s3b, 2048, 1, t4_2048);
        // layer 4: s3@W3
        gemm_splitk_kernel<<<dim3(8, 8, 8), blk, 0, stream>>>(s3b, WbT3, 2048, nullptr, nullptr, 0, 256, part, 1024);
        reduce_update_kernel<<<rg1024, rblk, 0, stream>>>(part, 8, b4p, s4f, s4f, s4b, 1024, 1, t4_1024);
    }

    // --- strip padding into d_out [1024,1000] ---
    out_copy_kernel<<<(1024 * 1000 + 255) / 256, 256, 0, stream>>>(s4f, out);
}